// Round 4
// baseline (1736.535 us; speedup 1.0000x reference)
//
#include <hip/hip_runtime.h>

// RNNBlock: h_t = relu(x_t @ W + h_{t-1} @ U + b) over reversed T, then
// out = relu(h @ W1 + b1).  B=65536, T=79, F=8, C=DW=256.
//
// R4 = R2's structure (512 thr / 8 waves / 64 rows / wave owns 32 cols,
// bf[17] = 68 VGPRs) + the R3 lesson: occupancy must be PINNED with
// amdgpu_waves_per_eu, not __launch_bounds__.  (4,4) -> 128-reg budget/wave,
// 4 waves/SIMD, 2 blocks/CU (LDS 64KB).  Register need ~123 <= 128 -> no
// spill (R2 spilled because the allocator targeted 8 waves/EU = 64 regs;
// R3's nf=2 needed ~160 V-side > 128V/128A split and spilled ~4 dw/step:
// WRITE 424MB vs 67MB ideal).
// Epilogue: plain ds_write_b16 (R2-measured SQ_LDS_BANK_CONFLICT = 0; the
// R3 DPP b32-pack created 8-way write conflicts, 2.07e7 cyc).
//
// MFMA v_mfma_f32_32x32x16_f16 layouts (learn_hip verified):
//   A[m][k]: m = lane&31, k = 8*(lane>>5) + j
//   B[k][n]: k = 8*(lane>>5) + j, n = lane&31
//   C/D    : col = lane&31, row = (reg&3) + 8*(reg>>2) + 4*(lane>>5)

#define B_ROWS 65536
#define T_STEPS 79
#define F_IN 8
#define C_DIM 256

typedef _Float16 h16;
typedef __attribute__((ext_vector_type(8))) _Float16 half8;
typedef __attribute__((ext_vector_type(16))) float f32x16;
typedef __attribute__((ext_vector_type(4))) float f32x4;

// LDS element index for h[r][c] (fp16), 16B-granule XOR swizzle.
// byte addr = r*512 + (((c>>3) ^ (r&31)) * 16) + (c&7)*2
// Reads (b128, r=lane-varying, c fixed): max 2-way  -> free (m136).
// Writes (b16, r fixed/lane, c=lane-varying): 2-way -> free. Measured 0.
__device__ __forceinline__ int lds_idx(int r, int c) {
  return (r << 8) + ((((c >> 3) ^ (r & 31)) << 3) | (c & 7));
}

// B-fragments for the 272x256 augmented weight, this wave's column n.
// rows 0..255 = M (U or W1), 256..263 = Wx (or 0), 264 = bias, 265..271 = 0.
__device__ __forceinline__ void load_bfrags(half8 bf[17],
                                            const float* __restrict__ M,
                                            const float* __restrict__ Wx,
                                            const float* __restrict__ bias,
                                            int n, int q) {
  #pragma unroll
  for (int kf = 0; kf < 16; ++kf) {
    const int k0 = 16 * kf + 8 * q;
    half8 v;
    #pragma unroll
    for (int j = 0; j < 8; ++j)
      v[j] = (h16)M[(size_t)(k0 + j) * C_DIM + n];
    bf[kf] = v;
  }
  half8 v;
  #pragma unroll
  for (int j = 0; j < 8; ++j) v[j] = (h16)0.f;
  if (q == 0) {
    if (Wx) {
      #pragma unroll
      for (int j = 0; j < 8; ++j) v[j] = (h16)Wx[j * C_DIM + n];
    }
  } else {
    v[0] = (h16)bias[n];  // k=264 pairs with A-side constant 1.0
  }
  bf[16] = v;
}

__global__ __launch_bounds__(512)
__attribute__((amdgpu_waves_per_eu(4, 4)))
void rnn_fused(const float* __restrict__ x, const float* __restrict__ W,
               const float* __restrict__ U, const float* __restrict__ b,
               const float* __restrict__ W1, const float* __restrict__ b1,
               float* __restrict__ out) {
  __shared__ alignas(16) h16 hbuf[2][64 * 256];  // 2 x 32 KB

  const int tid = threadIdx.x;
  const int lane = tid & 63;
  const int wave = tid >> 6;        // 0..7, owns cols [32w, 32w+32)
  const int l31 = lane & 31;
  const int q = lane >> 5;
  const int row0 = blockIdx.x << 6; // 64 batch rows per block
  const int n = (wave << 5) + l31;  // this lane's output column

  half8 bf[17];
  load_bfrags(bf, U, W, b, n, q);

  int buf = 0;
  #pragma unroll 1
  for (int s = 0; s < T_STEPS; ++s) {
    // augmented A fragment: q==0 lanes carry x_t (fp32->fp16), q==1 carry
    // [1,0..] for the bias slot. Global loads issued before the barrier.
    const int t = T_STEPS - 1 - s;  // go_backwards
    half8 xa[2];
    #pragma unroll
    for (int mf = 0; mf < 2; ++mf) {
      half8 v;
      if (q == 0) {
        const float* xp = x + (size_t)(row0 + 32 * mf + l31) * (T_STEPS * F_IN)
                            + (size_t)t * F_IN;
        const f32x4* xp4 = (const f32x4*)xp;
        const f32x4 lo = xp4[0], hi = xp4[1];
        v[0] = (h16)lo[0]; v[1] = (h16)lo[1]; v[2] = (h16)lo[2]; v[3] = (h16)lo[3];
        v[4] = (h16)hi[0]; v[5] = (h16)hi[1]; v[6] = (h16)hi[2]; v[7] = (h16)hi[3];
      } else {
        #pragma unroll
        for (int j = 0; j < 8; ++j) v[j] = (h16)0.f;
        v[0] = (h16)1.f;
      }
      xa[mf] = v;
    }

    __syncthreads();  // h(s-1) writes visible in hbuf[buf]

    f32x16 acc[2];
    #pragma unroll
    for (int mf = 0; mf < 2; ++mf)
      acc[mf] = __builtin_amdgcn_mfma_f32_32x32x16_f16(
          xa[mf], bf[16], (f32x16)(0.f), 0, 0, 0);

    if (s > 0) {  // h_0 = 0
      const h16* hb = hbuf[buf];
      const int c0 = 8 * q;
      #pragma unroll
      for (int kf = 0; kf < 16; ++kf) {
        #pragma unroll
        for (int mf = 0; mf < 2; ++mf) {
          const half8 a =
              *(const half8*)&hb[lds_idx(32 * mf + l31, 16 * kf + c0)];
          acc[mf] = __builtin_amdgcn_mfma_f32_32x32x16_f16(
              a, bf[kf], acc[mf], 0, 0, 0);
        }
      }
    }

    // epilogue: relu -> fp16 -> other LDS buffer (32 ds_write_b16/wave,
    // measured conflict-free)
    h16* hn = hbuf[buf ^ 1];
    #pragma unroll
    for (int mf = 0; mf < 2; ++mf) {
      #pragma unroll
      for (int reg = 0; reg < 16; ++reg) {
        const float v = fmaxf(acc[mf][reg], 0.f);
        const int rr = (reg & 3) + ((reg >> 2) << 3) + (q << 2) + (mf << 5);
        hn[lds_idx(rr, n)] = (h16)v;
      }
    }
    buf ^= 1;
  }

  // final Dense(256, relu): same GEMM step with W1/b1, x rows zeroed
  load_bfrags(bf, W1, nullptr, b1, n, q);
  half8 xa;
  #pragma unroll
  for (int j = 0; j < 8; ++j) xa[j] = (h16)0.f;
  if (q == 1) xa[0] = (h16)1.f;

  __syncthreads();

  f32x16 acc[2];
  #pragma unroll
  for (int mf = 0; mf < 2; ++mf)
    acc[mf] = __builtin_amdgcn_mfma_f32_32x32x16_f16(
        xa, bf[16], (f32x16)(0.f), 0, 0, 0);

  {
    const h16* hb = hbuf[buf];
    const int c0 = 8 * q;
    #pragma unroll
    for (int kf = 0; kf < 16; ++kf) {
      #pragma unroll
      for (int mf = 0; mf < 2; ++mf) {
        const half8 a =
            *(const half8*)&hb[lds_idx(32 * mf + l31, 16 * kf + c0)];
        acc[mf] = __builtin_amdgcn_mfma_f32_32x32x16_f16(
            a, bf[kf], acc[mf], 0, 0, 0);
      }
    }
  }

  #pragma unroll
  for (int mf = 0; mf < 2; ++mf) {
    #pragma unroll
    for (int reg = 0; reg < 16; ++reg) {
      const float v = fmaxf(acc[mf][reg], 0.f);
      const int rr = (reg & 3) + ((reg >> 2) << 3) + (q << 2) + (mf << 5);
      out[(size_t)(row0 + rr) * C_DIM + n] = v;
    }
  }
}

extern "C" void kernel_launch(void* const* d_in, const int* in_sizes, int n_in,
                              void* d_out, int out_size, void* d_ws, size_t ws_size,
                              hipStream_t stream) {
  const float* x  = (const float*)d_in[0];
  const float* W  = (const float*)d_in[1];
  const float* U  = (const float*)d_in[2];
  const float* b  = (const float*)d_in[3];
  const float* W1 = (const float*)d_in[4];
  const float* b1 = (const float*)d_in[5];
  float* out = (float*)d_out;

  rnn_fused<<<B_ROWS / 64, 512, 0, stream>>>(x, W, U, b, W1, b1, out);
}

// Round 5
// 962.026 us; speedup vs baseline: 1.8051x; 1.8051x over previous
//
#include <hip/hip_runtime.h>

// RNNBlock: h_t = relu(x_t @ W + h_{t-1} @ U + b) over reversed T, then
// out = relu(h @ W1 + b1).  B=65536, T=79, F=8, C=DW=256.
//
// R5 = R4's structure with waves_per_eu(2,2).
// SPLIT LAW (R2/R3/R4 counter evidence): with MFMA builtins, the allocator
// gives arch-VGPRs only HALF the per-wave unified budget (even V/A split):
//   (4,4)->budget 128->V=64  (R4: bf[17]=68 didn't fit -> 2.6GB scratch reads)
//   (2,2)->budget 256->V=128 (R3 showed V=128 in CSV)
// This config: V-need ~91 (bf 68 + xa 8 + addr) <= 128, A-need 32 <= 128.
// 8 waves/CU (1 resident block), DS-pipe-bound model ~330-420us floor.
//
// Block = 512 thr (8 waves) x 64 batch rows; wave owns 32 output channels;
// weights register-resident as bf[17] (K augmented to 272 = 256 h + 8 x +
// 1 bias + 7 zero). h exchanged via double-buffered LDS fp16 (2 x 32 KB),
// 16B-granule XOR swizzle: b128 reads / b16 writes measured conflict-free.
//
// MFMA v_mfma_f32_32x32x16_f16 layouts (learn_hip verified):
//   A[m][k]: m = lane&31, k = 8*(lane>>5) + j
//   B[k][n]: k = 8*(lane>>5) + j, n = lane&31
//   C/D    : col = lane&31, row = (reg&3) + 8*(reg>>2) + 4*(lane>>5)

#define B_ROWS 65536
#define T_STEPS 79
#define F_IN 8
#define C_DIM 256

typedef _Float16 h16;
typedef __attribute__((ext_vector_type(8))) _Float16 half8;
typedef __attribute__((ext_vector_type(16))) float f32x16;
typedef __attribute__((ext_vector_type(4))) float f32x4;

// LDS element index for h[r][c] (fp16), 16B-granule XOR swizzle.
// byte addr = r*512 + (((c>>3) ^ (r&31)) * 16) + (c&7)*2
__device__ __forceinline__ int lds_idx(int r, int c) {
  return (r << 8) + ((((c >> 3) ^ (r & 31)) << 3) | (c & 7));
}

// B-fragments for the 272x256 augmented weight, this wave's column n.
// rows 0..255 = M (U or W1), 256..263 = Wx (or 0), 264 = bias, 265..271 = 0.
__device__ __forceinline__ void load_bfrags(half8 bf[17],
                                            const float* __restrict__ M,
                                            const float* __restrict__ Wx,
                                            const float* __restrict__ bias,
                                            int n, int q) {
  #pragma unroll
  for (int kf = 0; kf < 16; ++kf) {
    const int k0 = 16 * kf + 8 * q;
    half8 v;
    #pragma unroll
    for (int j = 0; j < 8; ++j)
      v[j] = (h16)M[(size_t)(k0 + j) * C_DIM + n];
    bf[kf] = v;
  }
  half8 v;
  #pragma unroll
  for (int j = 0; j < 8; ++j) v[j] = (h16)0.f;
  if (q == 0) {
    if (Wx) {
      #pragma unroll
      for (int j = 0; j < 8; ++j) v[j] = (h16)Wx[j * C_DIM + n];
    }
  } else {
    v[0] = (h16)bias[n];  // k=264 pairs with A-side constant 1.0
  }
  bf[16] = v;
}

__global__ __launch_bounds__(512)
__attribute__((amdgpu_waves_per_eu(2, 2)))
void rnn_fused(const float* __restrict__ x, const float* __restrict__ W,
               const float* __restrict__ U, const float* __restrict__ b,
               const float* __restrict__ W1, const float* __restrict__ b1,
               float* __restrict__ out) {
  __shared__ alignas(16) h16 hbuf[2][64 * 256];  // 2 x 32 KB

  const int tid = threadIdx.x;
  const int lane = tid & 63;
  const int wave = tid >> 6;        // 0..7, owns cols [32w, 32w+32)
  const int l31 = lane & 31;
  const int q = lane >> 5;
  const int row0 = blockIdx.x << 6; // 64 batch rows per block
  const int n = (wave << 5) + l31;  // this lane's output column

  half8 bf[17];
  load_bfrags(bf, U, W, b, n, q);

  int buf = 0;
  #pragma unroll 1
  for (int s = 0; s < T_STEPS; ++s) {
    // augmented A fragment: q==0 lanes carry x_t (fp32->fp16), q==1 carry
    // [1,0..] for the bias slot. Global loads issued before the barrier.
    const int t = T_STEPS - 1 - s;  // go_backwards
    half8 xa[2];
    #pragma unroll
    for (int mf = 0; mf < 2; ++mf) {
      half8 v;
      if (q == 0) {
        const float* xp = x + (size_t)(row0 + 32 * mf + l31) * (T_STEPS * F_IN)
                            + (size_t)t * F_IN;
        const f32x4* xp4 = (const f32x4*)xp;
        const f32x4 lo = xp4[0], hi = xp4[1];
        v[0] = (h16)lo[0]; v[1] = (h16)lo[1]; v[2] = (h16)lo[2]; v[3] = (h16)lo[3];
        v[4] = (h16)hi[0]; v[5] = (h16)hi[1]; v[6] = (h16)hi[2]; v[7] = (h16)hi[3];
      } else {
        #pragma unroll
        for (int j = 0; j < 8; ++j) v[j] = (h16)0.f;
        v[0] = (h16)1.f;
      }
      xa[mf] = v;
    }

    __syncthreads();  // h(s-1) writes visible in hbuf[buf]

    f32x16 acc[2];
    #pragma unroll
    for (int mf = 0; mf < 2; ++mf)
      acc[mf] = __builtin_amdgcn_mfma_f32_32x32x16_f16(
          xa[mf], bf[16], (f32x16)(0.f), 0, 0, 0);

    if (s > 0) {  // h_0 = 0
      const h16* hb = hbuf[buf];
      const int c0 = 8 * q;
      #pragma unroll
      for (int kf = 0; kf < 16; ++kf) {
        #pragma unroll
        for (int mf = 0; mf < 2; ++mf) {
          const half8 a =
              *(const half8*)&hb[lds_idx(32 * mf + l31, 16 * kf + c0)];
          acc[mf] = __builtin_amdgcn_mfma_f32_32x32x16_f16(
              a, bf[kf], acc[mf], 0, 0, 0);
        }
      }
    }

    // epilogue: relu -> fp16 -> other LDS buffer (32 ds_write_b16/wave,
    // measured conflict-free)
    h16* hn = hbuf[buf ^ 1];
    #pragma unroll
    for (int mf = 0; mf < 2; ++mf) {
      #pragma unroll
      for (int reg = 0; reg < 16; ++reg) {
        const float v = fmaxf(acc[mf][reg], 0.f);
        const int rr = (reg & 3) + ((reg >> 2) << 3) + (q << 2) + (mf << 5);
        hn[lds_idx(rr, n)] = (h16)v;
      }
    }
    buf ^= 1;
  }

  // final Dense(256, relu): same GEMM step with W1/b1, x rows zeroed
  load_bfrags(bf, W1, nullptr, b1, n, q);
  half8 xa;
  #pragma unroll
  for (int j = 0; j < 8; ++j) xa[j] = (h16)0.f;
  if (q == 1) xa[0] = (h16)1.f;

  __syncthreads();

  f32x16 acc[2];
  #pragma unroll
  for (int mf = 0; mf < 2; ++mf)
    acc[mf] = __builtin_amdgcn_mfma_f32_32x32x16_f16(
        xa, bf[16], (f32x16)(0.f), 0, 0, 0);

  {
    const h16* hb = hbuf[buf];
    const int c0 = 8 * q;
    #pragma unroll
    for (int kf = 0; kf < 16; ++kf) {
      #pragma unroll
      for (int mf = 0; mf < 2; ++mf) {
        const half8 a =
            *(const half8*)&hb[lds_idx(32 * mf + l31, 16 * kf + c0)];
        acc[mf] = __builtin_amdgcn_mfma_f32_32x32x16_f16(
            a, bf[kf], acc[mf], 0, 0, 0);
      }
    }
  }

  #pragma unroll
  for (int mf = 0; mf < 2; ++mf) {
    #pragma unroll
    for (int reg = 0; reg < 16; ++reg) {
      const float v = fmaxf(acc[mf][reg], 0.f);
      const int rr = (reg & 3) + ((reg >> 2) << 3) + (q << 2) + (mf << 5);
      out[(size_t)(row0 + rr) * C_DIM + n] = v;
    }
  }
}

extern "C" void kernel_launch(void* const* d_in, const int* in_sizes, int n_in,
                              void* d_out, int out_size, void* d_ws, size_t ws_size,
                              hipStream_t stream) {
  const float* x  = (const float*)d_in[0];
  const float* W  = (const float*)d_in[1];
  const float* U  = (const float*)d_in[2];
  const float* b  = (const float*)d_in[3];
  const float* W1 = (const float*)d_in[4];
  const float* b1 = (const float*)d_in[5];
  float* out = (float*)d_out;

  rnn_fused<<<B_ROWS / 64, 512, 0, stream>>>(x, W, U, b, W1, b1, out);
}